// Round 3
// baseline (295.087 us; speedup 1.0000x reference)
//
#include <hip/hip_runtime.h>

// MaskHeadNetwork: per-instance dynamic 1x1 conv chain 16 -> 8 -> 8 -> 1
// instance_embedding: [200, 217] f32   (w0 16x8 | b0 8 | w1 8x8 | b1 8 | w2 8 | b2 1)
// pixel_embedding:    [200, 128, 128, 16] f32
// output:             [200, 128, 128] f32

constexpr int NI = 200;
constexpr int HW = 128 * 128;
constexpr int PE = 16;
constexpr int CH = 8;
constexpr int NP = PE * CH + CH + (CH * CH + CH) + (CH + 1);  // 217

constexpr int THREADS = 256;
constexpr int PPT = 4;                      // pixels per thread
constexpr int PIX_PER_BLOCK = THREADS * PPT;  // 1024
constexpr int BLOCKS_PER_INST = HW / PIX_PER_BLOCK;  // 16

// param offsets
constexpr int OFF_W0 = 0;          // [16][8]
constexpr int OFF_B0 = 128;        // [8]
constexpr int OFF_W1 = 136;        // [8][8]
constexpr int OFF_B1 = 200;        // [8]
constexpr int OFF_W2 = 208;        // [8]
constexpr int OFF_B2 = 216;        // [1]

__global__ __launch_bounds__(THREADS) void maskhead_kernel(
    const float* __restrict__ inst,
    const float* __restrict__ pix,
    float* __restrict__ out)
{
    __shared__ float sp[NP];
    const int n = blockIdx.x / BLOCKS_PER_INST;
    const int chunk = blockIdx.x % BLOCKS_PER_INST;
    const int t = threadIdx.x;

    if (t < NP) sp[t] = inst[n * NP + t];
    __syncthreads();

    const size_t pixBase = (size_t)n * HW + (size_t)chunk * PIX_PER_BLOCK;

    // ---- load 4 pixels x 16 channels as float4 ----
    float x[PPT][PE];
#pragma unroll
    for (int p = 0; p < PPT; ++p) {
        const float4* src =
            reinterpret_cast<const float4*>(pix + (pixBase + (size_t)p * THREADS + t) * PE);
#pragma unroll
        for (int q = 0; q < 4; ++q) {
            float4 v = src[q];
            x[p][q * 4 + 0] = v.x;
            x[p][q * 4 + 1] = v.y;
            x[p][q * 4 + 2] = v.z;
            x[p][q * 4 + 3] = v.w;
        }
    }

    // ---- layer 0: 16 -> 8, relu ----
    float a[PPT][CH];
    {
        float4 blo = *reinterpret_cast<const float4*>(&sp[OFF_B0]);
        float4 bhi = *reinterpret_cast<const float4*>(&sp[OFF_B0 + 4]);
#pragma unroll
        for (int p = 0; p < PPT; ++p) {
            a[p][0] = blo.x; a[p][1] = blo.y; a[p][2] = blo.z; a[p][3] = blo.w;
            a[p][4] = bhi.x; a[p][5] = bhi.y; a[p][6] = bhi.z; a[p][7] = bhi.w;
        }
#pragma unroll
        for (int c = 0; c < PE; ++c) {
            float4 wlo = *reinterpret_cast<const float4*>(&sp[OFF_W0 + c * CH]);
            float4 whi = *reinterpret_cast<const float4*>(&sp[OFF_W0 + c * CH + 4]);
#pragma unroll
            for (int p = 0; p < PPT; ++p) {
                const float xv = x[p][c];
                a[p][0] = fmaf(xv, wlo.x, a[p][0]);
                a[p][1] = fmaf(xv, wlo.y, a[p][1]);
                a[p][2] = fmaf(xv, wlo.z, a[p][2]);
                a[p][3] = fmaf(xv, wlo.w, a[p][3]);
                a[p][4] = fmaf(xv, whi.x, a[p][4]);
                a[p][5] = fmaf(xv, whi.y, a[p][5]);
                a[p][6] = fmaf(xv, whi.z, a[p][6]);
                a[p][7] = fmaf(xv, whi.w, a[p][7]);
            }
        }
#pragma unroll
        for (int p = 0; p < PPT; ++p)
#pragma unroll
            for (int k = 0; k < CH; ++k) a[p][k] = fmaxf(a[p][k], 0.0f);
    }

    // ---- layer 1: 8 -> 8, relu ----
    float y[PPT][CH];
    {
        float4 blo = *reinterpret_cast<const float4*>(&sp[OFF_B1]);
        float4 bhi = *reinterpret_cast<const float4*>(&sp[OFF_B1 + 4]);
#pragma unroll
        for (int p = 0; p < PPT; ++p) {
            y[p][0] = blo.x; y[p][1] = blo.y; y[p][2] = blo.z; y[p][3] = blo.w;
            y[p][4] = bhi.x; y[p][5] = bhi.y; y[p][6] = bhi.z; y[p][7] = bhi.w;
        }
#pragma unroll
        for (int c = 0; c < CH; ++c) {
            float4 wlo = *reinterpret_cast<const float4*>(&sp[OFF_W1 + c * CH]);
            float4 whi = *reinterpret_cast<const float4*>(&sp[OFF_W1 + c * CH + 4]);
#pragma unroll
            for (int p = 0; p < PPT; ++p) {
                const float xv = a[p][c];
                y[p][0] = fmaf(xv, wlo.x, y[p][0]);
                y[p][1] = fmaf(xv, wlo.y, y[p][1]);
                y[p][2] = fmaf(xv, wlo.z, y[p][2]);
                y[p][3] = fmaf(xv, wlo.w, y[p][3]);
                y[p][4] = fmaf(xv, whi.x, y[p][4]);
                y[p][5] = fmaf(xv, whi.y, y[p][5]);
                y[p][6] = fmaf(xv, whi.z, y[p][6]);
                y[p][7] = fmaf(xv, whi.w, y[p][7]);
            }
        }
#pragma unroll
        for (int p = 0; p < PPT; ++p)
#pragma unroll
            for (int k = 0; k < CH; ++k) y[p][k] = fmaxf(y[p][k], 0.0f);
    }

    // ---- layer 2: 8 -> 1 (no relu) ----
    {
        float4 wlo = *reinterpret_cast<const float4*>(&sp[OFF_W2]);
        float4 whi = *reinterpret_cast<const float4*>(&sp[OFF_W2 + 4]);
        const float b2 = sp[OFF_B2];
#pragma unroll
        for (int p = 0; p < PPT; ++p) {
            float o = b2;
            o = fmaf(y[p][0], wlo.x, o);
            o = fmaf(y[p][1], wlo.y, o);
            o = fmaf(y[p][2], wlo.z, o);
            o = fmaf(y[p][3], wlo.w, o);
            o = fmaf(y[p][4], whi.x, o);
            o = fmaf(y[p][5], whi.y, o);
            o = fmaf(y[p][6], whi.z, o);
            o = fmaf(y[p][7], whi.w, o);
            out[pixBase + (size_t)p * THREADS + t] = o;
        }
    }
}

extern "C" void kernel_launch(void* const* d_in, const int* in_sizes, int n_in,
                              void* d_out, int out_size, void* d_ws, size_t ws_size,
                              hipStream_t stream) {
    const float* inst = (const float*)d_in[0];  // [200, 217]
    const float* pix  = (const float*)d_in[1];  // [200, 128, 128, 16]
    float* out        = (float*)d_out;          // [200, 128, 128]

    const int grid = NI * BLOCKS_PER_INST;  // 3200
    maskhead_kernel<<<grid, THREADS, 0, stream>>>(inst, pix, out);
}

// Round 4
// 288.562 us; speedup vs baseline: 1.0226x; 1.0226x over previous
//
#include <hip/hip_runtime.h>

// MaskHeadNetwork: per-instance dynamic 1x1 conv chain 16 -> 8 -> 8 -> 1
// instance_embedding: [200, 217] f32   (w0 16x8 | b0 8 | w1 8x8 | b1 8 | w2 8 | b2 1)
// pixel_embedding:    [200, 128, 128, 16] f32
// output:             [200, 128, 128] f32
//
// Coalescing-first design: lane i always loads float4 #(base+i)  (lane-contiguous,
// 1 KB/instr dense). A 4-lane group owns one pixel; lane j holds channels 4j..4j+3.
// Layer0: per-lane partial (32 FMA) + shfl_xor(1),shfl_xor(2) butterfly.
// Layer1: 8 outputs split 2/lane (register-sliced weights). Layer2: 2-FMA partial +
// butterfly. 4 iters/wave, then one fully-coalesced 64-float store per wave.

constexpr int NI = 200;
constexpr int HW = 128 * 128;
constexpr int PE = 16;
constexpr int CH = 8;
constexpr int NP = PE * CH + CH + (CH * CH + CH) + (CH + 1);  // 217

constexpr int THREADS = 256;
constexpr int PIX_PER_WAVE = 64;                       // 16 pixels/iter x 4 iters
constexpr int PIX_PER_BLOCK = (THREADS / 64) * PIX_PER_WAVE;  // 256
constexpr int BLOCKS_PER_INST = HW / PIX_PER_BLOCK;    // 64

constexpr int OFF_W0 = 0;          // [16][8]
constexpr int OFF_B0 = 128;        // [8]
constexpr int OFF_W1 = 136;        // [8][8]
constexpr int OFF_B1 = 200;        // [8]
constexpr int OFF_W2 = 208;        // [8]
constexpr int OFF_B2 = 216;        // [1]

__global__ __launch_bounds__(THREADS) void maskhead_kernel(
    const float* __restrict__ inst,
    const float* __restrict__ pix,
    float* __restrict__ out)
{
    __shared__ float sp[NP];
    const int n = blockIdx.x / BLOCKS_PER_INST;
    const int chunk = blockIdx.x % BLOCKS_PER_INST;
    const int t = threadIdx.x;

    if (t < NP) sp[t] = inst[n * NP + t];
    __syncthreads();

    const int lane = t & 63;
    const int wave = t >> 6;
    const int j = lane & 3;    // quarter of the pixel this lane owns
    const int g = lane >> 2;   // pixel-group 0..15 within the iter

    // ---- per-lane parameter slices (registers, loaded once) ----
    // layer0: rows 4j..4j+3 of w0 (this lane's input channels)
    float w0s[4][CH];
#pragma unroll
    for (int c = 0; c < 4; ++c) {
        float4 lo = *reinterpret_cast<const float4*>(&sp[OFF_W0 + (4 * j + c) * CH]);
        float4 hi = *reinterpret_cast<const float4*>(&sp[OFF_W0 + (4 * j + c) * CH + 4]);
        w0s[c][0] = lo.x; w0s[c][1] = lo.y; w0s[c][2] = lo.z; w0s[c][3] = lo.w;
        w0s[c][4] = hi.x; w0s[c][5] = hi.y; w0s[c][6] = hi.z; w0s[c][7] = hi.w;
    }
    float b0s[CH];
    {
        float4 lo = *reinterpret_cast<const float4*>(&sp[OFF_B0]);
        float4 hi = *reinterpret_cast<const float4*>(&sp[OFF_B0 + 4]);
        b0s[0] = lo.x; b0s[1] = lo.y; b0s[2] = lo.z; b0s[3] = lo.w;
        b0s[4] = hi.x; b0s[5] = hi.y; b0s[6] = hi.z; b0s[7] = hi.w;
    }
    // layer1: this lane computes y[2j] and y[2j+1]
    float w1s[CH][2];
#pragma unroll
    for (int m = 0; m < CH; ++m) {
        w1s[m][0] = sp[OFF_W1 + m * CH + 2 * j];
        w1s[m][1] = sp[OFF_W1 + m * CH + 2 * j + 1];
    }
    const float b1s0 = sp[OFF_B1 + 2 * j];
    const float b1s1 = sp[OFF_B1 + 2 * j + 1];
    const float w2s0 = sp[OFF_W2 + 2 * j];
    const float w2s1 = sp[OFF_W2 + 2 * j + 1];
    const float b2   = sp[OFF_B2];

    const size_t pixBase = (size_t)n * HW + (size_t)chunk * PIX_PER_BLOCK
                         + (size_t)wave * PIX_PER_WAVE;
    const float4* src = reinterpret_cast<const float4*>(pix) + pixBase * 4 + lane;

    float r[4];
#pragma unroll
    for (int k = 0; k < 4; ++k) {
        // lane-contiguous load: float4 index = pixBase*4 + k*64 + lane
        const float4 v = src[k * 64];
        const float xx[4] = {v.x, v.y, v.z, v.w};

        // ---- layer 0 partial: this lane's 4 channels into all 8 outputs ----
        float acc[CH];
#pragma unroll
        for (int q = 0; q < CH; ++q) acc[q] = 0.0f;
#pragma unroll
        for (int c = 0; c < 4; ++c)
#pragma unroll
            for (int q = 0; q < CH; ++q)
                acc[q] = fmaf(xx[c], w0s[c][q], acc[q]);

        // butterfly-sum across the 4-lane group
#pragma unroll
        for (int q = 0; q < CH; ++q) acc[q] += __shfl_xor(acc[q], 1);
#pragma unroll
        for (int q = 0; q < CH; ++q) acc[q] += __shfl_xor(acc[q], 2);

        // bias + relu (full a[8] now replicated in every lane of the group)
#pragma unroll
        for (int q = 0; q < CH; ++q) acc[q] = fmaxf(acc[q] + b0s[q], 0.0f);

        // ---- layer 1: this lane's 2 outputs ----
        float y0 = b1s0, y1 = b1s1;
#pragma unroll
        for (int m = 0; m < CH; ++m) {
            y0 = fmaf(acc[m], w1s[m][0], y0);
            y1 = fmaf(acc[m], w1s[m][1], y1);
        }
        y0 = fmaxf(y0, 0.0f);
        y1 = fmaxf(y1, 0.0f);

        // ---- layer 2 partial + butterfly ----
        float o = fmaf(y1, w2s1, y0 * w2s0);
        o += __shfl_xor(o, 1);
        o += __shfl_xor(o, 2);
        r[k] = o + b2;
    }

    // ---- store: lane i writes pixel (i&3)*16 + (i>>2) -> 64 consecutive floats/wave
    const float oval = (j == 0) ? r[0] : (j == 1) ? r[1] : (j == 2) ? r[2] : r[3];
    out[pixBase + (size_t)(j * 16 + g)] = oval;
}

extern "C" void kernel_launch(void* const* d_in, const int* in_sizes, int n_in,
                              void* d_out, int out_size, void* d_ws, size_t ws_size,
                              hipStream_t stream) {
    const float* inst = (const float*)d_in[0];  // [200, 217]
    const float* pix  = (const float*)d_in[1];  // [200, 128, 128, 16]
    float* out        = (float*)d_out;          // [200, 128, 128]

    const int grid = NI * BLOCKS_PER_INST;  // 12800
    maskhead_kernel<<<grid, THREADS, 0, stream>>>(inst, pix, out);
}